// Round 1
// baseline (11224.726 us; speedup 1.0000x reference)
//
#include <hip/hip_runtime.h>

#define H 64
#define NUM_GRAPHS 64

// ---------------------------------------------------------------------------
// deg[dst] += w  (layer-1 collapses to a scalar weighted in-degree)
__global__ void deg_kernel(const int* __restrict__ dst, const float* __restrict__ w,
                           float* __restrict__ deg, int E) {
    int e = blockIdx.x * 256 + threadIdx.x;
    if (e < E) unsafeAtomicAdd(&deg[dst[e]], w[e]);
}

// x1[i,c] = relu(deg[i]*W1[c] + b1[c])
__global__ void layer1_kernel(const float* __restrict__ deg, const float* __restrict__ W1,
                              const float* __restrict__ b1, float* __restrict__ x, int N) {
    int gid = blockIdx.x * 256 + threadIdx.x;
    if (gid >= N * H) return;
    int i = gid >> 6, c = gid & 63;
    float v = deg[i] * W1[c] + b1[c];
    x[gid] = v > 0.f ? v : 0.f;
}

// h = x @ W   (N x 64) @ (64 x 64), W row-major
// block = 256 threads = 4 nodes x 64 cols; W staged in LDS
__global__ void gemm_kernel(const float* __restrict__ x, const float* __restrict__ W,
                            float* __restrict__ h, int N) {
    __shared__ float Ws[64][64];
    __shared__ float xs[4][64];
    int tid = threadIdx.x;
#pragma unroll
    for (int i = 0; i < 16; ++i) {
        int idx = i * 256 + tid;
        Ws[idx >> 6][idx & 63] = W[idx];
    }
    int n = tid >> 6;       // 0..3
    int c = tid & 63;       // 0..63
    int node = blockIdx.x * 4 + n;
    if (node < N) xs[n][c] = x[(size_t)node * H + c];
    __syncthreads();
    if (node >= N) return;
    float acc = 0.f;
#pragma unroll
    for (int k = 0; k < 64; ++k) acc += xs[n][k] * Ws[k][c];
    h[(size_t)node * H + c] = acc;
}

// out[dst,:] += h[src,:] * w   — 16 threads per edge, float4 gather, 4 atomics each
__global__ void scatter_kernel(const int* __restrict__ src, const int* __restrict__ dst,
                               const float* __restrict__ w, const float* __restrict__ h,
                               float* __restrict__ out, int E) {
    long long gid = (long long)blockIdx.x * 256 + threadIdx.x;
    int e = (int)(gid >> 4);
    if (e >= E) return;
    int part = (int)(gid & 15);
    int s = src[e], d = dst[e];
    float ww = w[e];
    const float4 hv = *reinterpret_cast<const float4*>(h + (size_t)s * H + part * 4);
    float* o = out + (size_t)d * H + part * 4;
    unsafeAtomicAdd(o + 0, hv.x * ww);
    unsafeAtomicAdd(o + 1, hv.y * ww);
    unsafeAtomicAdd(o + 2, hv.z * ww);
    unsafeAtomicAdd(o + 3, hv.w * ww);
}

// x = relu(x + b), float4-vectorized over N*64
__global__ void bias_relu_kernel(float* __restrict__ x, const float* __restrict__ b, int N) {
    int gid = blockIdx.x * 256 + threadIdx.x;   // over N*16 float4s
    if (gid >= N * 16) return;
    float4 v = reinterpret_cast<float4*>(x)[gid];
    int c4 = (gid & 15) * 4;
    v.x = fmaxf(v.x + b[c4 + 0], 0.f);
    v.y = fmaxf(v.y + b[c4 + 1], 0.f);
    v.z = fmaxf(v.z + b[c4 + 2], 0.f);
    v.w = fmaxf(v.w + b[c4 + 3], 0.f);
    reinterpret_cast<float4*>(x)[gid] = v;
}

// per-node dot with lin_w, LDS-binned segmented sum into 64 graphs
__global__ void pool_kernel(const float* __restrict__ x, const int* __restrict__ batch,
                            const float* __restrict__ linw, float* __restrict__ gsum,
                            float* __restrict__ gcnt, int N) {
    __shared__ float bins[NUM_GRAPHS];
    __shared__ float cnts[NUM_GRAPHS];
    int tid = threadIdx.x;
    if (tid < NUM_GRAPHS) { bins[tid] = 0.f; cnts[tid] = 0.f; }
    __syncthreads();
    int node = blockIdx.x * 256 + tid;
    if (node < N) {
        const float4* xr = reinterpret_cast<const float4*>(x + (size_t)node * H);
        const float4* lw = reinterpret_cast<const float4*>(linw);
        float acc = 0.f;
#pragma unroll
        for (int k = 0; k < 16; ++k) {
            float4 a = xr[k], b = lw[k];
            acc += a.x * b.x + a.y * b.y + a.z * b.z + a.w * b.w;
        }
        int g = batch[node];
        atomicAdd(&bins[g], acc);
        atomicAdd(&cnts[g], 1.f);
    }
    __syncthreads();
    if (tid < NUM_GRAPHS) {
        if (bins[tid] != 0.f || cnts[tid] != 0.f) {
            unsafeAtomicAdd(&gsum[tid], bins[tid]);
            unsafeAtomicAdd(&gcnt[tid], cnts[tid]);
        }
    }
}

__global__ void final_kernel(const float* __restrict__ gsum, const float* __restrict__ gcnt,
                             const float* __restrict__ lin_b, float* __restrict__ out) {
    int g = threadIdx.x;
    if (g < NUM_GRAPHS) out[g] = gsum[g] / fmaxf(gcnt[g], 1.f) + lin_b[0];
}

extern "C" void kernel_launch(void* const* d_in, const int* in_sizes, int n_in,
                              void* d_out, int out_size, void* d_ws, size_t ws_size,
                              hipStream_t stream) {
    const int*   edge_index = (const int*)d_in[0];
    const float* ew    = (const float*)d_in[1];
    const int*   batch = (const int*)d_in[2];
    const float* W1    = (const float*)d_in[4];
    const float* b1    = (const float*)d_in[5];
    const float* Wl[4] = {(const float*)d_in[6], (const float*)d_in[8],
                          (const float*)d_in[10], (const float*)d_in[12]};
    const float* bl[4] = {(const float*)d_in[7], (const float*)d_in[9],
                          (const float*)d_in[11], (const float*)d_in[13]};
    const float* linw  = (const float*)d_in[14];
    const float* linb  = (const float*)d_in[15];

    const int E = in_sizes[1];
    const int N = in_sizes[2];
    const int* src = edge_index;
    const int* dst = edge_index + E;

    float* bufA = (float*)d_ws;                 // N*H
    float* bufB = bufA + (size_t)N * H;         // N*H
    float* deg  = bufB + (size_t)N * H;         // N
    float* gsum = deg + N;                      // 64
    float* gcnt = gsum + NUM_GRAPHS;            // 64

    // ---- layer 1 (collapsed): deg_w then broadcastized linear+relu
    hipMemsetAsync(deg, 0, (size_t)N * sizeof(float), stream);
    deg_kernel<<<(E + 255) / 256, 256, 0, stream>>>(dst, ew, deg, E);
    layer1_kernel<<<(N * H + 255) / 256, 256, 0, stream>>>(deg, W1, b1, bufA, N);

    // ---- layers 2..5
    for (int l = 0; l < 4; ++l) {
        gemm_kernel<<<(N + 3) / 4, 256, 0, stream>>>(bufA, Wl[l], bufB, N);
        hipMemsetAsync(bufA, 0, (size_t)N * H * sizeof(float), stream);
        long long total = (long long)E * 16;
        scatter_kernel<<<(int)((total + 255) / 256), 256, 0, stream>>>(src, dst, ew, bufB, bufA, E);
        bias_relu_kernel<<<(N * 16 + 255) / 256, 256, 0, stream>>>(bufA, bl[l], N);
    }

    // ---- mean-pool per graph + final linear
    hipMemsetAsync(gsum, 0, 2 * NUM_GRAPHS * sizeof(float), stream);
    pool_kernel<<<(N + 255) / 256, 256, 0, stream>>>(bufA, batch, linw, gsum, gcnt, N);
    final_kernel<<<1, 64, 0, stream>>>(gsum, gcnt, linb, (float*)d_out);
}

// Round 2
// 1473.865 us; speedup vs baseline: 7.6158x; 7.6158x over previous
//
#include <hip/hip_runtime.h>

#define H 64
#define NUM_GRAPHS 64
#define SCAN_T 1024

// ---------------------------------------------------------------------------
// cnt[dst]++  (histogram for CSR build)
__global__ void hist_kernel(const int* __restrict__ dst, int* __restrict__ cnt, int E) {
    int e = blockIdx.x * 256 + threadIdx.x;
    if (e < E) atomicAdd(&cnt[dst[e]], 1);
}

// single-block inclusive scan -> rowptr (exclusive in rowptr[0..N]) + wcur (=exclusive)
__global__ void scan_kernel(const int* __restrict__ cnt, int* __restrict__ rowptr,
                            int* __restrict__ wcur, int N) {
    __shared__ int s[SCAN_T];
    __shared__ int carry;
    int tid = threadIdx.x;
    if (tid == 0) carry = 0;
    __syncthreads();
    for (int base = 0; base < N; base += SCAN_T) {
        int i = base + tid;
        int v = (i < N) ? cnt[i] : 0;
        s[tid] = v;
        __syncthreads();
        for (int off = 1; off < SCAN_T; off <<= 1) {
            int t = (tid >= off) ? s[tid - off] : 0;
            __syncthreads();
            s[tid] += t;
            __syncthreads();
        }
        int incl = s[tid];
        int c = carry;
        if (i < N) {
            rowptr[i + 1] = c + incl;
            wcur[i] = c + incl - v;
        }
        __syncthreads();
        if (tid == SCAN_T - 1) carry = c + incl;
        __syncthreads();
    }
    if (tid == 0) rowptr[0] = 0;
}

// scatter edges into CSR slots: csr[pos] = {src, bits(w)}
__global__ void fill_kernel(const int* __restrict__ src, const int* __restrict__ dst,
                            const float* __restrict__ w, int* __restrict__ wcur,
                            int2* __restrict__ csr, int E) {
    int e = blockIdx.x * 256 + threadIdx.x;
    if (e >= E) return;
    int d = dst[e];
    int pos = atomicAdd(&wcur[d], 1);
    csr[pos] = make_int2(src[e], __float_as_int(w[e]));
}

// layer 1 collapses: x = ones@W1 -> x1[i,c] = relu(degw[i]*W1[c]+b1[c]);
// degw from CSR row sum (wave per row, lanes stride edges, shuffle reduce)
__global__ void layer1_kernel(const int* __restrict__ rowptr, const int2* __restrict__ csr,
                              const float* __restrict__ W1, const float* __restrict__ b1,
                              float* __restrict__ out, int N) {
    int lane = threadIdx.x & 63, wid = threadIdx.x >> 6;
    int row = blockIdx.x * 4 + wid;
    if (row >= N) return;
    int beg = rowptr[row], end = rowptr[row + 1];
    float s = 0.f;
    for (int e = beg + lane; e < end; e += 64) s += __int_as_float(csr[e].y);
#pragma unroll
    for (int off = 32; off; off >>= 1) s += __shfl_xor(s, off);
    float v = s * W1[lane] + b1[lane];
    out[(size_t)row * H + lane] = fmaxf(v, 0.f);
}

// fused layer: out[d,:] = relu( (sum_e w_e * x[src_e,:]) @ W + b )
// (aggregation commutes with the linear transform)
// wave per dst row; lane = channel; matvec via LDS broadcast.
__global__ void layer_kernel(const int* __restrict__ rowptr, const int2* __restrict__ csr,
                             const float* __restrict__ x, const float* __restrict__ W,
                             const float* __restrict__ b, float* __restrict__ out, int N) {
    __shared__ float Ws[H * H];     // 16 KB
    __shared__ float aggs[4][H];    // 1 KB
    int tid = threadIdx.x;
    {
        const float4* W4 = reinterpret_cast<const float4*>(W);
        float4* Ws4 = reinterpret_cast<float4*>(Ws);
        for (int i = tid; i < H * H / 4; i += 256) Ws4[i] = W4[i];
    }
    __syncthreads();
    int lane = tid & 63, wid = tid >> 6;
    int row = blockIdx.x * 4 + wid;
    if (row >= N) return;
    int beg = rowptr[row], end = rowptr[row + 1];
    float agg = 0.f;
    int e = beg;
    for (; e + 1 < end; e += 2) {      // unroll-by-2: two independent gathers in flight
        int2 e0 = csr[e], e1 = csr[e + 1];
        float x0 = x[e0.x * H + lane];
        float x1 = x[e1.x * H + lane];
        agg += __int_as_float(e0.y) * x0;
        agg += __int_as_float(e1.y) * x1;
    }
    if (e < end) {
        int2 e0 = csr[e];
        agg += __int_as_float(e0.y) * x[e0.x * H + lane];
    }
    // matvec: acc[c] = b[c] + sum_k agg[k] * W[k][c]
    aggs[wid][lane] = agg;            // same-wave LDS, compiler inserts lgkmcnt wait
    float acc = b[lane];
#pragma unroll
    for (int k = 0; k < H; ++k) acc += aggs[wid][k] * Ws[k * H + lane];
    out[(size_t)row * H + lane] = fmaxf(acc, 0.f);
}

// per-node dot with lin_w, LDS-binned segmented sum into 64 graphs
__global__ void pool_kernel(const float* __restrict__ x, const int* __restrict__ batch,
                            const float* __restrict__ linw, float* __restrict__ gsum,
                            float* __restrict__ gcnt, int N) {
    __shared__ float bins[NUM_GRAPHS];
    __shared__ float cnts[NUM_GRAPHS];
    int tid = threadIdx.x;
    if (tid < NUM_GRAPHS) { bins[tid] = 0.f; cnts[tid] = 0.f; }
    __syncthreads();
    int node = blockIdx.x * 256 + tid;
    if (node < N) {
        const float4* xr = reinterpret_cast<const float4*>(x + (size_t)node * H);
        const float4* lw = reinterpret_cast<const float4*>(linw);
        float acc = 0.f;
#pragma unroll
        for (int k = 0; k < 16; ++k) {
            float4 a = xr[k], b = lw[k];
            acc += a.x * b.x + a.y * b.y + a.z * b.z + a.w * b.w;
        }
        int g = batch[node];
        atomicAdd(&bins[g], acc);
        atomicAdd(&cnts[g], 1.f);
    }
    __syncthreads();
    if (tid < NUM_GRAPHS) {
        if (bins[tid] != 0.f || cnts[tid] != 0.f) {
            unsafeAtomicAdd(&gsum[tid], bins[tid]);
            unsafeAtomicAdd(&gcnt[tid], cnts[tid]);
        }
    }
}

__global__ void final_kernel(const float* __restrict__ gsum, const float* __restrict__ gcnt,
                             const float* __restrict__ lin_b, float* __restrict__ out) {
    int g = threadIdx.x;
    if (g < NUM_GRAPHS) out[g] = gsum[g] / fmaxf(gcnt[g], 1.f) + lin_b[0];
}

extern "C" void kernel_launch(void* const* d_in, const int* in_sizes, int n_in,
                              void* d_out, int out_size, void* d_ws, size_t ws_size,
                              hipStream_t stream) {
    const int*   edge_index = (const int*)d_in[0];
    const float* ew    = (const float*)d_in[1];
    const int*   batch = (const int*)d_in[2];
    const float* W1    = (const float*)d_in[4];
    const float* b1    = (const float*)d_in[5];
    const float* Wl[4] = {(const float*)d_in[6], (const float*)d_in[8],
                          (const float*)d_in[10], (const float*)d_in[12]};
    const float* bl[4] = {(const float*)d_in[7], (const float*)d_in[9],
                          (const float*)d_in[11], (const float*)d_in[13]};
    const float* linw  = (const float*)d_in[14];
    const float* linb  = (const float*)d_in[15];

    const int E = in_sizes[1];
    const int N = in_sizes[2];
    const int* src = edge_index;
    const int* dst = edge_index + E;

    // workspace layout (all fp32/int32; int2 csr placed first for 8B alignment)
    int2*  csr    = (int2*)d_ws;                       // E
    float* bufA   = (float*)(csr + E);                 // N*H
    float* bufB   = bufA + (size_t)N * H;              // N*H
    int*   rowptr = (int*)(bufB + (size_t)N * H);      // N+1
    int*   cnt    = rowptr + (N + 1);                  // N
    int*   wcur   = cnt + N;                           // N
    float* gsum   = (float*)(wcur + N);                // 64
    float* gcnt   = gsum + NUM_GRAPHS;                 // 64

    // ---- CSR build (once; reused by all 5 layers)
    hipMemsetAsync(cnt, 0, (size_t)N * sizeof(int), stream);
    hist_kernel<<<(E + 255) / 256, 256, 0, stream>>>(dst, cnt, E);
    scan_kernel<<<1, SCAN_T, 0, stream>>>(cnt, rowptr, wcur, N);
    fill_kernel<<<(E + 255) / 256, 256, 0, stream>>>(src, dst, ew, wcur, csr, E);

    // ---- layer 1 (collapsed: input is all-ones through 1->64 linear)
    layer1_kernel<<<(N + 3) / 4, 256, 0, stream>>>(rowptr, csr, W1, b1, bufA, N);

    // ---- layers 2..5 (fused gather + matvec + bias + relu)
    float* in = bufA;
    float* outb = bufB;
    for (int l = 0; l < 4; ++l) {
        layer_kernel<<<(N + 3) / 4, 256, 0, stream>>>(rowptr, csr, in, Wl[l], bl[l], outb, N);
        float* t = in; in = outb; outb = t;
    }
    // final node features now in `in`

    // ---- mean-pool per graph + final linear
    hipMemsetAsync(gsum, 0, 2 * NUM_GRAPHS * sizeof(float), stream);
    pool_kernel<<<(N + 255) / 256, 256, 0, stream>>>(in, batch, linw, gsum, gcnt, N);
    final_kernel<<<1, 64, 0, stream>>>(gsum, gcnt, linb, (float*)d_out);
}

// Round 3
// 866.476 us; speedup vs baseline: 12.9545x; 1.7010x over previous
//
#include <hip/hip_runtime.h>

#define H 64
#define NUM_GRAPHS 64
#define BSHIFT 8
#define BSIZE 256          // nodes per bucket
#define MAXNB 512          // supports N <= 131072
#define CHUNK 8192         // edges per partition block

// ---------------------------------------------------------------------------
// A0: per-chunk LDS bucket histogram -> global bucketCnt
__global__ __launch_bounds__(1024) void bhist_kernel(const int* __restrict__ dst,
        int* __restrict__ bucketCnt, int E, int NB) {
    __shared__ int h[MAXNB];
    int tid = threadIdx.x;
    for (int i = tid; i < NB; i += 1024) h[i] = 0;
    __syncthreads();
    int base = blockIdx.x * CHUNK;
    int end = min(base + CHUNK, E);
    for (int e = base + tid; e < end; e += 1024)
        atomicAdd(&h[dst[e] >> BSHIFT], 1);
    __syncthreads();
    for (int i = tid; i < NB; i += 1024)
        if (h[i]) atomicAdd(&bucketCnt[i], h[i]);
}

// A1: tiny scan over NB buckets -> bucketPtr (exclusive bounds), bucketCur
__global__ __launch_bounds__(MAXNB) void bscan_kernel(const int* __restrict__ bucketCnt,
        int* __restrict__ bucketPtr, int* __restrict__ bucketCur, int NB) {
    __shared__ int s[MAXNB];
    int tid = threadIdx.x;
    int v = (tid < NB) ? bucketCnt[tid] : 0;
    s[tid] = v;
    __syncthreads();
    for (int off = 1; off < MAXNB; off <<= 1) {
        int t = (tid >= off) ? s[tid - off] : 0;
        __syncthreads();
        s[tid] += t;
        __syncthreads();
    }
    if (tid < NB) {
        bucketPtr[tid + 1] = s[tid];
        bucketCur[tid] = s[tid] - v;    // exclusive prefix
    }
    if (tid == 0) bucketPtr[0] = 0;
}

// A2: partition edges into bucket regions; pack (dstLocal<<17 | src, w_bits)
__global__ __launch_bounds__(1024) void part_kernel(const int* __restrict__ src,
        const int* __restrict__ dst, const float* __restrict__ w,
        int* __restrict__ bucketCur, int2* __restrict__ bucketed, int E, int NB) {
    __shared__ int h[MAXNB];
    __shared__ int basev[MAXNB];
    int tid = threadIdx.x;
    for (int i = tid; i < NB; i += 1024) h[i] = 0;
    __syncthreads();
    int cbase = blockIdx.x * CHUNK;
    int cend = min(cbase + CHUNK, E);
    for (int e = cbase + tid; e < cend; e += 1024)
        atomicAdd(&h[dst[e] >> BSHIFT], 1);
    __syncthreads();
    for (int i = tid; i < NB; i += 1024) {
        int c = h[i];
        basev[i] = c ? atomicAdd(&bucketCur[i], c) : 0;
    }
    __syncthreads();
    for (int i = tid; i < NB; i += 1024) h[i] = 0;   // reuse as local cursor
    __syncthreads();
    for (int e = cbase + tid; e < cend; e += 1024) {
        int d = dst[e];
        int b = d >> BSHIFT;
        int slot = atomicAdd(&h[b], 1);
        bucketed[basev[b] + slot] =
            make_int2(((d & (BSIZE - 1)) << 17) | src[e], __float_as_int(w[e]));
    }
}

// B: per-bucket counting sort -> csr {src, w_bits} + rowptr (all LDS-local)
__global__ __launch_bounds__(512) void bsort_kernel(const int* __restrict__ bucketPtr,
        const int2* __restrict__ bucketed, int2* __restrict__ csr,
        int* __restrict__ rowptr, int N, int E) {
    __shared__ int cnt[BSIZE];
    __shared__ int pos[BSIZE];
    int b = blockIdx.x;
    int tid = threadIdx.x;
    int nodeBase = b << BSHIFT;
    int nNodes = min(BSIZE, N - nodeBase);
    if (tid < BSIZE) cnt[tid] = 0;
    __syncthreads();
    int ebeg = bucketPtr[b], eend = bucketPtr[b + 1];
    for (int e = ebeg + tid; e < eend; e += 512)
        atomicAdd(&cnt[bucketed[e].x >> 17], 1);
    __syncthreads();
    if (tid < BSIZE) pos[tid] = cnt[tid];
    __syncthreads();
    for (int off = 1; off < BSIZE; off <<= 1) {
        int t = (tid < BSIZE && tid >= off) ? pos[tid - off] : 0;
        __syncthreads();
        if (tid < BSIZE) pos[tid] += t;
        __syncthreads();
    }
    if (tid < nNodes)
        rowptr[nodeBase + tid] = ebeg + pos[tid] - cnt[tid];
    if (b == 0 && tid == 0) rowptr[N] = E;
    __syncthreads();
    if (tid < BSIZE) cnt[tid] = pos[tid] - cnt[tid];   // reuse as cursor
    __syncthreads();
    for (int e = ebeg + tid; e < eend; e += 512) {
        int2 v = bucketed[e];
        int slot = atomicAdd(&cnt[v.x >> 17], 1);
        csr[ebeg + slot] = make_int2(v.x & 0x1FFFF, v.y);
    }
}

// ---------------------------------------------------------------------------
// layer 1 collapses: x1[i,c] = relu(degw[i]*W1[c]+b1[c]), degw = row-sum of w
__global__ void layer1_kernel(const int* __restrict__ rowptr, const int2* __restrict__ csr,
                              const float* __restrict__ W1, const float* __restrict__ b1,
                              float* __restrict__ out, int N) {
    int lane = threadIdx.x & 63, wid = threadIdx.x >> 6;
    int row = blockIdx.x * 4 + wid;
    if (row >= N) return;
    int beg = rowptr[row], end = rowptr[row + 1];
    float s = 0.f;
    for (int e = beg + lane; e < end; e += 64) s += __int_as_float(csr[e].y);
#pragma unroll
    for (int off = 32; off; off >>= 1) s += __shfl_xor(s, off);
    float v = s * W1[lane] + b1[lane];
    out[(size_t)row * H + lane] = fmaxf(v, 0.f);
}

// fused layer: out[d,:] = relu( (sum_e w_e * x[src_e,:]) @ W + b )
// wave per dst row; lane = channel; matvec via readlane broadcast of agg
__global__ __launch_bounds__(256) void layer_kernel(const int* __restrict__ rowptr,
        const int2* __restrict__ csr, const float* __restrict__ x,
        const float* __restrict__ W, const float* __restrict__ b,
        float* __restrict__ out, int N) {
    __shared__ float Ws[H * H];     // 16 KB, row-major W[k][c]
    int tid = threadIdx.x;
    {
        const float4* W4 = reinterpret_cast<const float4*>(W);
        float4* Ws4 = reinterpret_cast<float4*>(Ws);
        for (int i = tid; i < H * H / 4; i += 256) Ws4[i] = W4[i];
    }
    __syncthreads();
    int lane = tid & 63, wid = tid >> 6;
    int row = blockIdx.x * 4 + wid;
    if (row >= N) return;
    int beg = rowptr[row], end = rowptr[row + 1];
    float agg = 0.f;
    int e = beg;
    for (; e + 3 < end; e += 4) {   // 4 independent gathers in flight
        int2 e0 = csr[e], e1 = csr[e + 1], e2 = csr[e + 2], e3 = csr[e + 3];
        float x0 = x[e0.x * H + lane];
        float x1 = x[e1.x * H + lane];
        float x2 = x[e2.x * H + lane];
        float x3 = x[e3.x * H + lane];
        agg += __int_as_float(e0.y) * x0 + __int_as_float(e1.y) * x1
             + __int_as_float(e2.y) * x2 + __int_as_float(e3.y) * x3;
    }
    for (; e < end; ++e) {
        int2 e0 = csr[e];
        agg += __int_as_float(e0.y) * x[e0.x * H + lane];
    }
    // matvec: acc[c] = b[c] + sum_k agg[k] * W[k][c]; agg[k] via v_readlane
    float acc = b[lane];
#pragma unroll
    for (int k = 0; k < H; ++k)
        acc += __shfl(agg, k) * Ws[k * H + lane];
    out[(size_t)row * H + lane] = fmaxf(acc, 0.f);
}

// per-node dot with lin_w, LDS-binned segmented sum into 64 graphs
__global__ void pool_kernel(const float* __restrict__ x, const int* __restrict__ batch,
                            const float* __restrict__ linw, float* __restrict__ gsum,
                            float* __restrict__ gcnt, int N) {
    __shared__ float bins[NUM_GRAPHS];
    __shared__ float cnts[NUM_GRAPHS];
    int tid = threadIdx.x;
    if (tid < NUM_GRAPHS) { bins[tid] = 0.f; cnts[tid] = 0.f; }
    __syncthreads();
    int node = blockIdx.x * 256 + tid;
    if (node < N) {
        const float4* xr = reinterpret_cast<const float4*>(x + (size_t)node * H);
        const float4* lw = reinterpret_cast<const float4*>(linw);
        float acc = 0.f;
#pragma unroll
        for (int k = 0; k < 16; ++k) {
            float4 a = xr[k], b = lw[k];
            acc += a.x * b.x + a.y * b.y + a.z * b.z + a.w * b.w;
        }
        int g = batch[node];
        atomicAdd(&bins[g], acc);
        atomicAdd(&cnts[g], 1.f);
    }
    __syncthreads();
    if (tid < NUM_GRAPHS) {
        if (bins[tid] != 0.f || cnts[tid] != 0.f) {
            unsafeAtomicAdd(&gsum[tid], bins[tid]);
            unsafeAtomicAdd(&gcnt[tid], cnts[tid]);
        }
    }
}

__global__ void final_kernel(const float* __restrict__ gsum, const float* __restrict__ gcnt,
                             const float* __restrict__ lin_b, float* __restrict__ out) {
    int g = threadIdx.x;
    if (g < NUM_GRAPHS) out[g] = gsum[g] / fmaxf(gcnt[g], 1.f) + lin_b[0];
}

extern "C" void kernel_launch(void* const* d_in, const int* in_sizes, int n_in,
                              void* d_out, int out_size, void* d_ws, size_t ws_size,
                              hipStream_t stream) {
    const int*   edge_index = (const int*)d_in[0];
    const float* ew    = (const float*)d_in[1];
    const int*   batch = (const int*)d_in[2];
    const float* W1    = (const float*)d_in[4];
    const float* b1    = (const float*)d_in[5];
    const float* Wl[4] = {(const float*)d_in[6], (const float*)d_in[8],
                          (const float*)d_in[10], (const float*)d_in[12]};
    const float* bl[4] = {(const float*)d_in[7], (const float*)d_in[9],
                          (const float*)d_in[11], (const float*)d_in[13]};
    const float* linw  = (const float*)d_in[14];
    const float* linb  = (const float*)d_in[15];

    const int E = in_sizes[1];
    const int N = in_sizes[2];
    const int* src = edge_index;
    const int* dst = edge_index + E;
    const int NB = (N + BSIZE - 1) >> BSHIFT;

    // workspace layout
    int2*  csr    = (int2*)d_ws;                       // E
    float* bufA   = (float*)(csr + E);                 // N*H
    float* bufB   = bufA + (size_t)N * H;              // N*H
    int2*  bucketed = (int2*)bufB;                     // alias (consumed pre-layer2)
    int*   rowptr = (int*)(bufB + (size_t)N * H);      // N+1
    int*   bucketCnt = rowptr + (N + 1);               // MAXNB
    int*   bucketPtr = bucketCnt + MAXNB;              // MAXNB+1
    int*   bucketCur = bucketPtr + MAXNB + 1;          // MAXNB
    float* gsum   = (float*)(bucketCur + MAXNB);       // 64
    float* gcnt   = gsum + NUM_GRAPHS;                 // 64

    const int chunks = (E + CHUNK - 1) / CHUNK;

    // ---- CSR build: bucketed counting sort (no global scan, L2-local scatter)
    hipMemsetAsync(bucketCnt, 0, MAXNB * sizeof(int), stream);
    bhist_kernel<<<chunks, 1024, 0, stream>>>(dst, bucketCnt, E, NB);
    bscan_kernel<<<1, MAXNB, 0, stream>>>(bucketCnt, bucketPtr, bucketCur, NB);
    part_kernel<<<chunks, 1024, 0, stream>>>(src, dst, ew, bucketCur, bucketed, E, NB);
    bsort_kernel<<<NB, 512, 0, stream>>>(bucketPtr, bucketed, csr, rowptr, N, E);

    // ---- layer 1 (collapsed: all-ones input through 1->64 linear)
    layer1_kernel<<<(N + 3) / 4, 256, 0, stream>>>(rowptr, csr, W1, b1, bufA, N);

    // ---- layers 2..5 (fused gather + matvec + bias + relu)
    float* in = bufA;
    float* outb = bufB;
    for (int l = 0; l < 4; ++l) {
        layer_kernel<<<(N + 3) / 4, 256, 0, stream>>>(rowptr, csr, in, Wl[l], bl[l], outb, N);
        float* t = in; in = outb; outb = t;
    }

    // ---- mean-pool per graph + final linear
    hipMemsetAsync(gsum, 0, 2 * NUM_GRAPHS * sizeof(float), stream);
    pool_kernel<<<(N + 255) / 256, 256, 0, stream>>>(in, batch, linw, gsum, gcnt, N);
    final_kernel<<<1, 64, 0, stream>>>(gsum, gcnt, linb, (float*)d_out);
}

// Round 4
// 854.020 us; speedup vs baseline: 13.1434x; 1.0146x over previous
//
#include <hip/hip_runtime.h>

#define H 64
#define NUM_GRAPHS 64
#define BSHIFT 8
#define BSIZE 256          // nodes per bucket
#define MAXNB 512          // supports N <= 131072
#define CHUNK 8192         // edges per partition block

typedef unsigned int uint;
typedef unsigned short ushort;

__device__ __forceinline__ float bf2f(ushort u) {
    return __uint_as_float(((uint)u) << 16);
}
__device__ __forceinline__ ushort f2bf(float f) {   // RNE
    uint b = __float_as_uint(f);
    b += 0x7FFFu + ((b >> 16) & 1u);
    return (ushort)(b >> 16);
}

// ---------------------------------------------------------------------------
// A0: per-chunk LDS bucket histogram -> global bucketCnt
__global__ __launch_bounds__(1024) void bhist_kernel(const int* __restrict__ dst,
        int* __restrict__ bucketCnt, int E, int NB) {
    __shared__ int h[MAXNB];
    int tid = threadIdx.x;
    for (int i = tid; i < NB; i += 1024) h[i] = 0;
    __syncthreads();
    int base = blockIdx.x * CHUNK;
    int end = min(base + CHUNK, E);
    for (int e = base + tid; e < end; e += 1024)
        atomicAdd(&h[dst[e] >> BSHIFT], 1);
    __syncthreads();
    for (int i = tid; i < NB; i += 1024)
        if (h[i]) atomicAdd(&bucketCnt[i], h[i]);
}

// A1: tiny scan over NB buckets -> bucketPtr (exclusive bounds), bucketCur
__global__ __launch_bounds__(MAXNB) void bscan_kernel(const int* __restrict__ bucketCnt,
        int* __restrict__ bucketPtr, int* __restrict__ bucketCur, int NB) {
    __shared__ int s[MAXNB];
    int tid = threadIdx.x;
    int v = (tid < NB) ? bucketCnt[tid] : 0;
    s[tid] = v;
    __syncthreads();
    for (int off = 1; off < MAXNB; off <<= 1) {
        int t = (tid >= off) ? s[tid - off] : 0;
        __syncthreads();
        s[tid] += t;
        __syncthreads();
    }
    if (tid < NB) {
        bucketPtr[tid + 1] = s[tid];
        bucketCur[tid] = s[tid] - v;    // exclusive prefix
    }
    if (tid == 0) bucketPtr[0] = 0;
}

// A2: partition edges into bucket regions; pack (dstLocal<<17 | src, w_bits)
__global__ __launch_bounds__(1024) void part_kernel(const int* __restrict__ src,
        const int* __restrict__ dst, const float* __restrict__ w,
        int* __restrict__ bucketCur, int2* __restrict__ bucketed, int E, int NB) {
    __shared__ int h[MAXNB];
    __shared__ int basev[MAXNB];
    int tid = threadIdx.x;
    for (int i = tid; i < NB; i += 1024) h[i] = 0;
    __syncthreads();
    int cbase = blockIdx.x * CHUNK;
    int cend = min(cbase + CHUNK, E);
    for (int e = cbase + tid; e < cend; e += 1024)
        atomicAdd(&h[dst[e] >> BSHIFT], 1);
    __syncthreads();
    for (int i = tid; i < NB; i += 1024) {
        int c = h[i];
        basev[i] = c ? atomicAdd(&bucketCur[i], c) : 0;
    }
    __syncthreads();
    for (int i = tid; i < NB; i += 1024) h[i] = 0;   // reuse as local cursor
    __syncthreads();
    for (int e = cbase + tid; e < cend; e += 1024) {
        int d = dst[e];
        int b = d >> BSHIFT;
        int slot = atomicAdd(&h[b], 1);
        bucketed[basev[b] + slot] =
            make_int2(((d & (BSIZE - 1)) << 17) | src[e], __float_as_int(w[e]));
    }
}

// B: per-bucket counting sort -> packed csr (src<<15 | bf16w) + rowptr
__global__ __launch_bounds__(512) void bsort_kernel(const int* __restrict__ bucketPtr,
        const int2* __restrict__ bucketed, uint* __restrict__ csr,
        int* __restrict__ rowptr, int N, int E) {
    __shared__ int cnt[BSIZE];
    __shared__ int pos[BSIZE];
    int b = blockIdx.x;
    int tid = threadIdx.x;
    int nodeBase = b << BSHIFT;
    int nNodes = min(BSIZE, N - nodeBase);
    if (tid < BSIZE) cnt[tid] = 0;
    __syncthreads();
    int ebeg = bucketPtr[b], eend = bucketPtr[b + 1];
    for (int e = ebeg + tid; e < eend; e += 512)
        atomicAdd(&cnt[bucketed[e].x >> 17], 1);
    __syncthreads();
    if (tid < BSIZE) pos[tid] = cnt[tid];
    __syncthreads();
    for (int off = 1; off < BSIZE; off <<= 1) {
        int t = (tid < BSIZE && tid >= off) ? pos[tid - off] : 0;
        __syncthreads();
        if (tid < BSIZE) pos[tid] += t;
        __syncthreads();
    }
    if (tid < nNodes)
        rowptr[nodeBase + tid] = ebeg + pos[tid] - cnt[tid];
    if (b == 0 && tid == 0) rowptr[N] = E;
    __syncthreads();
    if (tid < BSIZE) cnt[tid] = pos[tid] - cnt[tid];   // reuse as cursor
    __syncthreads();
    for (int e = ebeg + tid; e < eend; e += 512) {
        int2 v = bucketed[e];
        int slot = atomicAdd(&cnt[v.x >> 17], 1);
        uint wb = (uint)v.y;                          // fp32 bits, sign=0 (w in [0,1))
        wb += 0x7FFFu + ((wb >> 16) & 1u);            // RNE to bf16
        uint w15 = (wb >> 16) & 0x7FFFu;
        uint s   = (uint)(v.x & 0x1FFFF);
        csr[ebeg + slot] = (s << 15) | w15;
    }
}

// ---------------------------------------------------------------------------
// layer 1 collapses: x1[i,c] = relu(degw[i]*W1[c]+b1[c]), degw = row-sum of w
__global__ void layer1_kernel(const int* __restrict__ rowptr, const uint* __restrict__ csr,
                              const float* __restrict__ W1, const float* __restrict__ b1,
                              ushort* __restrict__ out, int N) {
    int lane = threadIdx.x & 63, wid = threadIdx.x >> 6;
    int row = blockIdx.x * 4 + wid;
    if (row >= N) return;
    int beg = rowptr[row], end = rowptr[row + 1];
    float s = 0.f;
    for (int e = beg + lane; e < end; e += 64) {
        uint p = __builtin_nontemporal_load(csr + e);
        s += __uint_as_float((p & 0x7FFFu) << 16);
    }
#pragma unroll
    for (int off = 32; off; off >>= 1) s += __shfl_xor(s, off);
    float v = s * W1[lane] + b1[lane];
    __builtin_nontemporal_store(f2bf(fmaxf(v, 0.f)), out + (size_t)row * H + lane);
}

// fused layer: out[d,:] = relu( (sum_e w_e * x[src_e,:]) @ W + b )
// wave per dst row; lane = channel; bf16 gather, fp32 accumulate
__global__ __launch_bounds__(256) void layer_kernel(const int* __restrict__ rowptr,
        const uint* __restrict__ csr, const ushort* __restrict__ x,
        const float* __restrict__ W, const float* __restrict__ b,
        ushort* __restrict__ out, int N) {
    __shared__ float Ws[H * H];     // 16 KB, row-major W[k][c]
    int tid = threadIdx.x;
    {
        const float4* W4 = reinterpret_cast<const float4*>(W);
        float4* Ws4 = reinterpret_cast<float4*>(Ws);
        for (int i = tid; i < H * H / 4; i += 256) Ws4[i] = W4[i];
    }
    __syncthreads();
    int lane = tid & 63, wid = tid >> 6;
    int row = blockIdx.x * 4 + wid;
    if (row >= N) return;
    int beg = rowptr[row], end = rowptr[row + 1];
    float agg = 0.f;
    int e = beg;
    for (; e + 3 < end; e += 4) {   // 4 independent gathers in flight
        uint p0 = __builtin_nontemporal_load(csr + e);
        uint p1 = __builtin_nontemporal_load(csr + e + 1);
        uint p2 = __builtin_nontemporal_load(csr + e + 2);
        uint p3 = __builtin_nontemporal_load(csr + e + 3);
        ushort u0 = x[(p0 >> 15) * H + lane];
        ushort u1 = x[(p1 >> 15) * H + lane];
        ushort u2 = x[(p2 >> 15) * H + lane];
        ushort u3 = x[(p3 >> 15) * H + lane];
        agg += __uint_as_float((p0 & 0x7FFFu) << 16) * bf2f(u0)
             + __uint_as_float((p1 & 0x7FFFu) << 16) * bf2f(u1)
             + __uint_as_float((p2 & 0x7FFFu) << 16) * bf2f(u2)
             + __uint_as_float((p3 & 0x7FFFu) << 16) * bf2f(u3);
    }
    for (; e < end; ++e) {
        uint p = __builtin_nontemporal_load(csr + e);
        agg += __uint_as_float((p & 0x7FFFu) << 16) * bf2f(x[(p >> 15) * H + lane]);
    }
    // matvec: acc[c] = b[c] + sum_k agg[k] * W[k][c]; agg[k] via v_readlane
    float acc = b[lane];
#pragma unroll
    for (int k = 0; k < H; ++k)
        acc += __shfl(agg, k) * Ws[k * H + lane];
    __builtin_nontemporal_store(f2bf(fmaxf(acc, 0.f)), out + (size_t)row * H + lane);
}

// per-node dot with lin_w, LDS-binned segmented sum into 64 graphs
__global__ void pool_kernel(const ushort* __restrict__ x, const int* __restrict__ batch,
                            const float* __restrict__ linw, float* __restrict__ gsum,
                            float* __restrict__ gcnt, int N) {
    __shared__ float bins[NUM_GRAPHS];
    __shared__ float cnts[NUM_GRAPHS];
    int tid = threadIdx.x;
    if (tid < NUM_GRAPHS) { bins[tid] = 0.f; cnts[tid] = 0.f; }
    __syncthreads();
    int node = blockIdx.x * 256 + tid;
    if (node < N) {
        const uint4* xv = reinterpret_cast<const uint4*>(x + (size_t)node * H);
        float acc = 0.f;
#pragma unroll
        for (int k = 0; k < 8; ++k) {          // 8 x uint4 = 64 bf16
            uint4 u = xv[k];
            int c = k * 8;
            acc += bf2f((ushort)(u.x & 0xFFFF)) * linw[c + 0]
                 + bf2f((ushort)(u.x >> 16))    * linw[c + 1]
                 + bf2f((ushort)(u.y & 0xFFFF)) * linw[c + 2]
                 + bf2f((ushort)(u.y >> 16))    * linw[c + 3]
                 + bf2f((ushort)(u.z & 0xFFFF)) * linw[c + 4]
                 + bf2f((ushort)(u.z >> 16))    * linw[c + 5]
                 + bf2f((ushort)(u.w & 0xFFFF)) * linw[c + 6]
                 + bf2f((ushort)(u.w >> 16))    * linw[c + 7];
        }
        int g = batch[node];
        atomicAdd(&bins[g], acc);
        atomicAdd(&cnts[g], 1.f);
    }
    __syncthreads();
    if (tid < NUM_GRAPHS) {
        if (bins[tid] != 0.f || cnts[tid] != 0.f) {
            unsafeAtomicAdd(&gsum[tid], bins[tid]);
            unsafeAtomicAdd(&gcnt[tid], cnts[tid]);
        }
    }
}

__global__ void final_kernel(const float* __restrict__ gsum, const float* __restrict__ gcnt,
                             const float* __restrict__ lin_b, float* __restrict__ out) {
    int g = threadIdx.x;
    if (g < NUM_GRAPHS) out[g] = gsum[g] / fmaxf(gcnt[g], 1.f) + lin_b[0];
}

extern "C" void kernel_launch(void* const* d_in, const int* in_sizes, int n_in,
                              void* d_out, int out_size, void* d_ws, size_t ws_size,
                              hipStream_t stream) {
    const int*   edge_index = (const int*)d_in[0];
    const float* ew    = (const float*)d_in[1];
    const int*   batch = (const int*)d_in[2];
    const float* W1    = (const float*)d_in[4];
    const float* b1    = (const float*)d_in[5];
    const float* Wl[4] = {(const float*)d_in[6], (const float*)d_in[8],
                          (const float*)d_in[10], (const float*)d_in[12]};
    const float* bl[4] = {(const float*)d_in[7], (const float*)d_in[9],
                          (const float*)d_in[11], (const float*)d_in[13]};
    const float* linw  = (const float*)d_in[14];
    const float* linb  = (const float*)d_in[15];

    const int E = in_sizes[1];
    const int N = in_sizes[2];
    const int* src = edge_index;
    const int* dst = edge_index + E;
    const int NB = (N + BSIZE - 1) >> BSHIFT;

    // workspace layout
    char* base = (char*)d_ws;
    uint* csr = (uint*)base;
    size_t csrBytes = (((size_t)E * 4) + 255) & ~(size_t)255;
    ushort* bufA = (ushort*)(base + csrBytes);
    size_t featBytes = (size_t)N * H * 2;
    ushort* bufB = bufA + (size_t)N * H;
    int2* bucketed = (int2*)bufA;                       // aliases bufA+bufB (build only)
    size_t span = 2 * featBytes;
    size_t bktBytes = (size_t)E * 8;
    if (bktBytes > span) span = bktBytes;
    span = (span + 255) & ~(size_t)255;
    char* tail = base + csrBytes + span;
    int* rowptr    = (int*)tail;                        // N+1
    int* bucketCnt = rowptr + (N + 1);                  // MAXNB
    int* bucketPtr = bucketCnt + MAXNB;                 // MAXNB+1
    int* bucketCur = bucketPtr + MAXNB + 1;             // MAXNB
    float* gsum    = (float*)(bucketCur + MAXNB);       // 64
    float* gcnt    = gsum + NUM_GRAPHS;                 // 64

    const int chunks = (E + CHUNK - 1) / CHUNK;

    // ---- CSR build: bucketed counting sort (no global scan, L2-local scatter)
    hipMemsetAsync(bucketCnt, 0, MAXNB * sizeof(int), stream);
    bhist_kernel<<<chunks, 1024, 0, stream>>>(dst, bucketCnt, E, NB);
    bscan_kernel<<<1, MAXNB, 0, stream>>>(bucketCnt, bucketPtr, bucketCur, NB);
    part_kernel<<<chunks, 1024, 0, stream>>>(src, dst, ew, bucketCur, bucketed, E, NB);
    bsort_kernel<<<NB, 512, 0, stream>>>(bucketPtr, bucketed, csr, rowptr, N, E);

    // ---- layer 1 (collapsed: all-ones input through 1->64 linear)
    layer1_kernel<<<(N + 3) / 4, 256, 0, stream>>>(rowptr, csr, W1, b1, bufA, N);

    // ---- layers 2..5 (fused gather + matvec + bias + relu), bf16 features
    ushort* in = bufA;
    ushort* outb = bufB;
    for (int l = 0; l < 4; ++l) {
        layer_kernel<<<(N + 3) / 4, 256, 0, stream>>>(rowptr, csr, in, Wl[l], bl[l], outb, N);
        ushort* t = in; in = outb; outb = t;
    }

    // ---- mean-pool per graph + final linear
    hipMemsetAsync(gsum, 0, 2 * NUM_GRAPHS * sizeof(float), stream);
    pool_kernel<<<(N + 255) / 256, 256, 0, stream>>>(in, batch, linw, gsum, gcnt, N);
    final_kernel<<<1, 64, 0, stream>>>(gsum, gcnt, linb, (float*)d_out);
}

// Round 5
// 475.397 us; speedup vs baseline: 23.6113x; 1.7964x over previous
//
#include <hip/hip_runtime.h>

#define H 64
#define NUM_GRAPHS 64
#define BSHIFT 8
#define BSIZE 256          // nodes per bucket
#define MAXNB 512          // supports N <= 131072
#define CHUNK 8192         // edges per partition block

typedef unsigned int uint;
typedef unsigned short ushort;

__device__ __forceinline__ float bf2f(ushort u) {
    return __uint_as_float(((uint)u) << 16);
}
__device__ __forceinline__ ushort f2bf(float f) {   // RNE
    uint b = __float_as_uint(f);
    b += 0x7FFFu + ((b >> 16) & 1u);
    return (ushort)(b >> 16);
}

// ---------------------------------------------------------------------------
// A0: per-chunk LDS bucket histogram -> global bucketCnt
__global__ __launch_bounds__(1024) void bhist_kernel(const int* __restrict__ dst,
        int* __restrict__ bucketCnt, int E, int NB) {
    __shared__ int h[MAXNB];
    int tid = threadIdx.x;
    for (int i = tid; i < NB; i += 1024) h[i] = 0;
    __syncthreads();
    int base = blockIdx.x * CHUNK;
    int end = min(base + CHUNK, E);
    for (int e = base + tid; e < end; e += 1024)
        atomicAdd(&h[dst[e] >> BSHIFT], 1);
    __syncthreads();
    for (int i = tid; i < NB; i += 1024)
        if (h[i]) atomicAdd(&bucketCnt[i], h[i]);
}

// A1: tiny scan over NB buckets -> bucketPtr (exclusive bounds), bucketCur
__global__ __launch_bounds__(MAXNB) void bscan_kernel(const int* __restrict__ bucketCnt,
        int* __restrict__ bucketPtr, int* __restrict__ bucketCur, int NB) {
    __shared__ int s[MAXNB];
    int tid = threadIdx.x;
    int v = (tid < NB) ? bucketCnt[tid] : 0;
    s[tid] = v;
    __syncthreads();
    for (int off = 1; off < MAXNB; off <<= 1) {
        int t = (tid >= off) ? s[tid - off] : 0;
        __syncthreads();
        s[tid] += t;
        __syncthreads();
    }
    if (tid < NB) {
        bucketPtr[tid + 1] = s[tid];
        bucketCur[tid] = s[tid] - v;    // exclusive prefix
    }
    if (tid == 0) bucketPtr[0] = 0;
}

// A2: partition edges into bucket regions; pack (dstLocal<<17 | src, w_bits)
__global__ __launch_bounds__(1024) void part_kernel(const int* __restrict__ src,
        const int* __restrict__ dst, const float* __restrict__ w,
        int* __restrict__ bucketCur, int2* __restrict__ bucketed, int E, int NB) {
    __shared__ int h[MAXNB];
    __shared__ int basev[MAXNB];
    int tid = threadIdx.x;
    for (int i = tid; i < NB; i += 1024) h[i] = 0;
    __syncthreads();
    int cbase = blockIdx.x * CHUNK;
    int cend = min(cbase + CHUNK, E);
    for (int e = cbase + tid; e < cend; e += 1024)
        atomicAdd(&h[dst[e] >> BSHIFT], 1);
    __syncthreads();
    for (int i = tid; i < NB; i += 1024) {
        int c = h[i];
        basev[i] = c ? atomicAdd(&bucketCur[i], c) : 0;
    }
    __syncthreads();
    for (int i = tid; i < NB; i += 1024) h[i] = 0;   // reuse as local cursor
    __syncthreads();
    for (int e = cbase + tid; e < cend; e += 1024) {
        int d = dst[e];
        int b = d >> BSHIFT;
        int slot = atomicAdd(&h[b], 1);
        bucketed[basev[b] + slot] =
            make_int2(((d & (BSIZE - 1)) << 17) | src[e], __float_as_int(w[e]));
    }
}

// B: per-bucket counting sort -> packed csr (src<<15 | bf16w) + rowptr
__global__ __launch_bounds__(512) void bsort_kernel(const int* __restrict__ bucketPtr,
        const int2* __restrict__ bucketed, uint* __restrict__ csr,
        int* __restrict__ rowptr, int N, int E) {
    __shared__ int cnt[BSIZE];
    __shared__ int pos[BSIZE];
    int b = blockIdx.x;
    int tid = threadIdx.x;
    int nodeBase = b << BSHIFT;
    int nNodes = min(BSIZE, N - nodeBase);
    if (tid < BSIZE) cnt[tid] = 0;
    __syncthreads();
    int ebeg = bucketPtr[b], eend = bucketPtr[b + 1];
    for (int e = ebeg + tid; e < eend; e += 512)
        atomicAdd(&cnt[bucketed[e].x >> 17], 1);
    __syncthreads();
    if (tid < BSIZE) pos[tid] = cnt[tid];
    __syncthreads();
    for (int off = 1; off < BSIZE; off <<= 1) {
        int t = (tid < BSIZE && tid >= off) ? pos[tid - off] : 0;
        __syncthreads();
        if (tid < BSIZE) pos[tid] += t;
        __syncthreads();
    }
    if (tid < nNodes)
        rowptr[nodeBase + tid] = ebeg + pos[tid] - cnt[tid];
    if (b == 0 && tid == 0) rowptr[N] = E;
    __syncthreads();
    if (tid < BSIZE) cnt[tid] = pos[tid] - cnt[tid];   // reuse as cursor
    __syncthreads();
    for (int e = ebeg + tid; e < eend; e += 512) {
        int2 v = bucketed[e];
        int slot = atomicAdd(&cnt[v.x >> 17], 1);
        uint wb = (uint)v.y;                          // fp32 bits, sign=0 (w in [0,1))
        wb += 0x7FFFu + ((wb >> 16) & 1u);            // RNE to bf16
        uint w15 = (wb >> 16) & 0x7FFFu;
        uint s   = (uint)(v.x & 0x1FFFF);
        csr[ebeg + slot] = (s << 15) | w15;
    }
}

// ---------------------------------------------------------------------------
// layer 1 collapses: x1[i,c] = relu(degw[i]*W1[c]+b1[c]), degw = row-sum of w
__global__ void layer1_kernel(const int* __restrict__ rowptr, const uint* __restrict__ csr,
                              const float* __restrict__ W1, const float* __restrict__ b1,
                              ushort* __restrict__ out, int N) {
    int lane = threadIdx.x & 63, wid = threadIdx.x >> 6;
    int row = blockIdx.x * 4 + wid;
    if (row >= N) return;
    int beg = rowptr[row], end = rowptr[row + 1];
    float s = 0.f;
    for (int e = beg + lane; e < end; e += 64) {
        uint p = __builtin_nontemporal_load(csr + e);
        s += __uint_as_float((p & 0x7FFFu) << 16);
    }
#pragma unroll
    for (int off = 32; off; off >>= 1) s += __shfl_xor(s, off);
    float v = s * W1[lane] + b1[lane];
    __builtin_nontemporal_store(f2bf(fmaxf(v, 0.f)), out + (size_t)row * H + lane);
}

// fused layer: out[d,:] = relu( (sum_e w_e * x[src_e,:]) @ W + b )
// wave per dst row; lane = channel. CSR row loaded COALESCED (lane l -> edge
// beg+l) into per-wave LDS, broadcast-read back -> gather addresses come from
// LDS, not a serial wave-uniform VMEM chain; 8 gathers in flight per group.
__global__ __launch_bounds__(256) void layer_kernel(const int* __restrict__ rowptr,
        const uint* __restrict__ csr, const ushort* __restrict__ x,
        const float* __restrict__ W, const float* __restrict__ b,
        ushort* __restrict__ out, int N) {
    __shared__ float Ws[H * H];     // 16 KB, row-major W[k][c]
    __shared__ uint pc[4][64];      // per-wave CSR row cache
    int tid = threadIdx.x;
    {
        const float4* W4 = reinterpret_cast<const float4*>(W);
        float4* Ws4 = reinterpret_cast<float4*>(Ws);
        for (int i = tid; i < H * H / 4; i += 256) Ws4[i] = W4[i];
    }
    __syncthreads();
    int lane = tid & 63, wid = tid >> 6;
    int row = blockIdx.x * 4 + wid;
    if (row >= N) return;
    int beg = rowptr[row], end = rowptr[row + 1];
    float agg = 0.f;
    for (int cbeg = beg; cbeg < end; cbeg += 64) {
        int idx = cbeg + lane;
        uint pv = 0u;                                  // pad: w=0, src=0 (safe)
        if (idx < end) pv = __builtin_nontemporal_load(csr + idx);
        pc[wid][lane] = pv;                            // same-wave write->read
        int cnt8 = (min(64, end - cbeg) + 7) & ~7;     // round up; pads are w=0
        for (int k = 0; k < cnt8; k += 8) {
            uint p0 = pc[wid][k + 0], p1 = pc[wid][k + 1];
            uint p2 = pc[wid][k + 2], p3 = pc[wid][k + 3];
            uint p4 = pc[wid][k + 4], p5 = pc[wid][k + 5];
            uint p6 = pc[wid][k + 6], p7 = pc[wid][k + 7];
            ushort u0 = x[(p0 >> 15) * H + lane];
            ushort u1 = x[(p1 >> 15) * H + lane];
            ushort u2 = x[(p2 >> 15) * H + lane];
            ushort u3 = x[(p3 >> 15) * H + lane];
            ushort u4 = x[(p4 >> 15) * H + lane];
            ushort u5 = x[(p5 >> 15) * H + lane];
            ushort u6 = x[(p6 >> 15) * H + lane];
            ushort u7 = x[(p7 >> 15) * H + lane];
            agg += __uint_as_float((p0 & 0x7FFFu) << 16) * bf2f(u0)
                 + __uint_as_float((p1 & 0x7FFFu) << 16) * bf2f(u1)
                 + __uint_as_float((p2 & 0x7FFFu) << 16) * bf2f(u2)
                 + __uint_as_float((p3 & 0x7FFFu) << 16) * bf2f(u3);
            agg += __uint_as_float((p4 & 0x7FFFu) << 16) * bf2f(u4)
                 + __uint_as_float((p5 & 0x7FFFu) << 16) * bf2f(u5)
                 + __uint_as_float((p6 & 0x7FFFu) << 16) * bf2f(u6)
                 + __uint_as_float((p7 & 0x7FFFu) << 16) * bf2f(u7);
        }
    }
    // matvec: acc[c] = b[c] + sum_k agg[k] * W[k][c]; agg[k] via v_readlane
    float acc = b[lane];
    uint aggb = __float_as_uint(agg);
#pragma unroll
    for (int k = 0; k < H; ++k)
        acc += __uint_as_float(__builtin_amdgcn_readlane(aggb, k)) * Ws[k * H + lane];
    __builtin_nontemporal_store(f2bf(fmaxf(acc, 0.f)), out + (size_t)row * H + lane);
}

// per-node dot with lin_w, LDS-binned segmented sum into 64 graphs
__global__ void pool_kernel(const ushort* __restrict__ x, const int* __restrict__ batch,
                            const float* __restrict__ linw, float* __restrict__ gsum,
                            float* __restrict__ gcnt, int N) {
    __shared__ float bins[NUM_GRAPHS];
    __shared__ float cnts[NUM_GRAPHS];
    int tid = threadIdx.x;
    if (tid < NUM_GRAPHS) { bins[tid] = 0.f; cnts[tid] = 0.f; }
    __syncthreads();
    int node = blockIdx.x * 256 + tid;
    if (node < N) {
        const uint4* xv = reinterpret_cast<const uint4*>(x + (size_t)node * H);
        float acc = 0.f;
#pragma unroll
        for (int k = 0; k < 8; ++k) {          // 8 x uint4 = 64 bf16
            uint4 u = xv[k];
            int c = k * 8;
            acc += bf2f((ushort)(u.x & 0xFFFF)) * linw[c + 0]
                 + bf2f((ushort)(u.x >> 16))    * linw[c + 1]
                 + bf2f((ushort)(u.y & 0xFFFF)) * linw[c + 2]
                 + bf2f((ushort)(u.y >> 16))    * linw[c + 3]
                 + bf2f((ushort)(u.z & 0xFFFF)) * linw[c + 4]
                 + bf2f((ushort)(u.z >> 16))    * linw[c + 5]
                 + bf2f((ushort)(u.w & 0xFFFF)) * linw[c + 6]
                 + bf2f((ushort)(u.w >> 16))    * linw[c + 7];
        }
        int g = batch[node];
        atomicAdd(&bins[g], acc);
        atomicAdd(&cnts[g], 1.f);
    }
    __syncthreads();
    if (tid < NUM_GRAPHS) {
        if (bins[tid] != 0.f || cnts[tid] != 0.f) {
            unsafeAtomicAdd(&gsum[tid], bins[tid]);
            unsafeAtomicAdd(&gcnt[tid], cnts[tid]);
        }
    }
}

__global__ void final_kernel(const float* __restrict__ gsum, const float* __restrict__ gcnt,
                             const float* __restrict__ lin_b, float* __restrict__ out) {
    int g = threadIdx.x;
    if (g < NUM_GRAPHS) out[g] = gsum[g] / fmaxf(gcnt[g], 1.f) + lin_b[0];
}

extern "C" void kernel_launch(void* const* d_in, const int* in_sizes, int n_in,
                              void* d_out, int out_size, void* d_ws, size_t ws_size,
                              hipStream_t stream) {
    const int*   edge_index = (const int*)d_in[0];
    const float* ew    = (const float*)d_in[1];
    const int*   batch = (const int*)d_in[2];
    const float* W1    = (const float*)d_in[4];
    const float* b1    = (const float*)d_in[5];
    const float* Wl[4] = {(const float*)d_in[6], (const float*)d_in[8],
                          (const float*)d_in[10], (const float*)d_in[12]};
    const float* bl[4] = {(const float*)d_in[7], (const float*)d_in[9],
                          (const float*)d_in[11], (const float*)d_in[13]};
    const float* linw  = (const float*)d_in[14];
    const float* linb  = (const float*)d_in[15];

    const int E = in_sizes[1];
    const int N = in_sizes[2];
    const int* src = edge_index;
    const int* dst = edge_index + E;
    const int NB = (N + BSIZE - 1) >> BSHIFT;

    // workspace layout
    char* base = (char*)d_ws;
    uint* csr = (uint*)base;
    size_t csrBytes = (((size_t)E * 4) + 255) & ~(size_t)255;
    ushort* bufA = (ushort*)(base + csrBytes);
    size_t featBytes = (size_t)N * H * 2;
    ushort* bufB = bufA + (size_t)N * H;
    int2* bucketed = (int2*)bufA;                       // aliases bufA+bufB (build only)
    size_t span = 2 * featBytes;
    size_t bktBytes = (size_t)E * 8;
    if (bktBytes > span) span = bktBytes;
    span = (span + 255) & ~(size_t)255;
    char* tail = base + csrBytes + span;
    int* rowptr    = (int*)tail;                        // N+1
    int* bucketCnt = rowptr + (N + 1);                  // MAXNB
    int* bucketPtr = bucketCnt + MAXNB;                 // MAXNB+1
    int* bucketCur = bucketPtr + MAXNB + 1;             // MAXNB
    float* gsum    = (float*)(bucketCur + MAXNB);       // 64
    float* gcnt    = gsum + NUM_GRAPHS;                 // 64

    const int chunks = (E + CHUNK - 1) / CHUNK;

    // ---- CSR build: bucketed counting sort (no global scan, L2-local scatter)
    hipMemsetAsync(bucketCnt, 0, MAXNB * sizeof(int), stream);
    bhist_kernel<<<chunks, 1024, 0, stream>>>(dst, bucketCnt, E, NB);
    bscan_kernel<<<1, MAXNB, 0, stream>>>(bucketCnt, bucketPtr, bucketCur, NB);
    part_kernel<<<chunks, 1024, 0, stream>>>(src, dst, ew, bucketCur, bucketed, E, NB);
    bsort_kernel<<<NB, 512, 0, stream>>>(bucketPtr, bucketed, csr, rowptr, N, E);

    // ---- layer 1 (collapsed: all-ones input through 1->64 linear)
    layer1_kernel<<<(N + 3) / 4, 256, 0, stream>>>(rowptr, csr, W1, b1, bufA, N);

    // ---- layers 2..5 (fused gather + matvec + bias + relu), bf16 features
    ushort* in = bufA;
    ushort* outb = bufB;
    for (int l = 0; l < 4; ++l) {
        layer_kernel<<<(N + 3) / 4, 256, 0, stream>>>(rowptr, csr, in, Wl[l], bl[l], outb, N);
        ushort* t = in; in = outb; outb = t;
    }

    // ---- mean-pool per graph + final linear
    hipMemsetAsync(gsum, 0, 2 * NUM_GRAPHS * sizeof(float), stream);
    pool_kernel<<<(N + 255) / 256, 256, 0, stream>>>(in, batch, linw, gsum, gcnt, N);
    final_kernel<<<1, 64, 0, stream>>>(gsum, gcnt, linb, (float*)d_out);
}

// Round 6
// 417.570 us; speedup vs baseline: 26.8811x; 1.1385x over previous
//
#include <hip/hip_runtime.h>

#define H 64
#define NUM_GRAPHS 64
#define BSHIFT 8
#define BSIZE 256          // nodes per bucket
#define MAXNB 512          // supports N <= 131072
#define CHUNK 8192         // edges per partition block
#define RPB 16             // rows per block in layer kernel

typedef unsigned int uint;
typedef unsigned short ushort;
typedef __attribute__((ext_vector_type(4))) float f32x4;
typedef __attribute__((ext_vector_type(8))) short short8;

__device__ __forceinline__ float bf2f(ushort u) {
    return __uint_as_float(((uint)u) << 16);
}
__device__ __forceinline__ ushort f2bf(float f) {   // RNE
    uint b = __float_as_uint(f);
    b += 0x7FFFu + ((b >> 16) & 1u);
    return (ushort)(b >> 16);
}

// ---------------------------------------------------------------------------
// A0: per-chunk LDS bucket histogram -> global bucketCnt
__global__ __launch_bounds__(1024) void bhist_kernel(const int* __restrict__ dst,
        int* __restrict__ bucketCnt, int E, int NB) {
    __shared__ int h[MAXNB];
    int tid = threadIdx.x;
    for (int i = tid; i < NB; i += 1024) h[i] = 0;
    __syncthreads();
    int base = blockIdx.x * CHUNK;
    int end = min(base + CHUNK, E);
    for (int e = base + tid; e < end; e += 1024)
        atomicAdd(&h[dst[e] >> BSHIFT], 1);
    __syncthreads();
    for (int i = tid; i < NB; i += 1024)
        if (h[i]) atomicAdd(&bucketCnt[i], h[i]);
}

// A1: tiny scan over NB buckets -> bucketPtr (exclusive bounds), bucketCur
__global__ __launch_bounds__(MAXNB) void bscan_kernel(const int* __restrict__ bucketCnt,
        int* __restrict__ bucketPtr, int* __restrict__ bucketCur, int NB) {
    __shared__ int s[MAXNB];
    int tid = threadIdx.x;
    int v = (tid < NB) ? bucketCnt[tid] : 0;
    s[tid] = v;
    __syncthreads();
    for (int off = 1; off < MAXNB; off <<= 1) {
        int t = (tid >= off) ? s[tid - off] : 0;
        __syncthreads();
        s[tid] += t;
        __syncthreads();
    }
    if (tid < NB) {
        bucketPtr[tid + 1] = s[tid];
        bucketCur[tid] = s[tid] - v;    // exclusive prefix
    }
    if (tid == 0) bucketPtr[0] = 0;
}

// A2: partition edges into bucket regions; pack (dstLocal<<17 | src, w_bits)
__global__ __launch_bounds__(1024) void part_kernel(const int* __restrict__ src,
        const int* __restrict__ dst, const float* __restrict__ w,
        int* __restrict__ bucketCur, int2* __restrict__ bucketed, int E, int NB) {
    __shared__ int h[MAXNB];
    __shared__ int basev[MAXNB];
    int tid = threadIdx.x;
    for (int i = tid; i < NB; i += 1024) h[i] = 0;
    __syncthreads();
    int cbase = blockIdx.x * CHUNK;
    int cend = min(cbase + CHUNK, E);
    for (int e = cbase + tid; e < cend; e += 1024)
        atomicAdd(&h[dst[e] >> BSHIFT], 1);
    __syncthreads();
    for (int i = tid; i < NB; i += 1024) {
        int c = h[i];
        basev[i] = c ? atomicAdd(&bucketCur[i], c) : 0;
    }
    __syncthreads();
    for (int i = tid; i < NB; i += 1024) h[i] = 0;   // reuse as local cursor
    __syncthreads();
    for (int e = cbase + tid; e < cend; e += 1024) {
        int d = dst[e];
        int b = d >> BSHIFT;
        int slot = atomicAdd(&h[b], 1);
        bucketed[basev[b] + slot] =
            make_int2(((d & (BSIZE - 1)) << 17) | src[e], __float_as_int(w[e]));
    }
}

// B: per-bucket counting sort -> packed csr (src<<15 | bf16w) + rowptr
__global__ __launch_bounds__(512) void bsort_kernel(const int* __restrict__ bucketPtr,
        const int2* __restrict__ bucketed, uint* __restrict__ csr,
        int* __restrict__ rowptr, int N, int E) {
    __shared__ int cnt[BSIZE];
    __shared__ int pos[BSIZE];
    int b = blockIdx.x;
    int tid = threadIdx.x;
    int nodeBase = b << BSHIFT;
    int nNodes = min(BSIZE, N - nodeBase);
    if (tid < BSIZE) cnt[tid] = 0;
    __syncthreads();
    int ebeg = bucketPtr[b], eend = bucketPtr[b + 1];
    for (int e = ebeg + tid; e < eend; e += 512)
        atomicAdd(&cnt[bucketed[e].x >> 17], 1);
    __syncthreads();
    if (tid < BSIZE) pos[tid] = cnt[tid];
    __syncthreads();
    for (int off = 1; off < BSIZE; off <<= 1) {
        int t = (tid < BSIZE && tid >= off) ? pos[tid - off] : 0;
        __syncthreads();
        if (tid < BSIZE) pos[tid] += t;
        __syncthreads();
    }
    if (tid < nNodes)
        rowptr[nodeBase + tid] = ebeg + pos[tid] - cnt[tid];
    if (b == 0 && tid == 0) rowptr[N] = E;
    __syncthreads();
    if (tid < BSIZE) cnt[tid] = pos[tid] - cnt[tid];   // reuse as cursor
    __syncthreads();
    for (int e = ebeg + tid; e < eend; e += 512) {
        int2 v = bucketed[e];
        int slot = atomicAdd(&cnt[v.x >> 17], 1);
        uint wb = (uint)v.y;                          // fp32 bits, sign=0 (w in [0,1))
        wb += 0x7FFFu + ((wb >> 16) & 1u);            // RNE to bf16
        uint w15 = (wb >> 16) & 0x7FFFu;
        uint s   = (uint)(v.x & 0x1FFFF);
        csr[ebeg + slot] = (s << 15) | w15;
    }
}

// ---------------------------------------------------------------------------
// layer 1 collapses: x1[i,c] = relu(degw[i]*W1[c]+b1[c]), degw = row-sum of w
__global__ void layer1_kernel(const int* __restrict__ rowptr, const uint* __restrict__ csr,
                              const float* __restrict__ W1, const float* __restrict__ b1,
                              ushort* __restrict__ out, int N) {
    int lane = threadIdx.x & 63, wid = threadIdx.x >> 6;
    int row = blockIdx.x * 4 + wid;
    if (row >= N) return;
    int beg = rowptr[row], end = rowptr[row + 1];
    float s = 0.f;
    for (int e = beg + lane; e < end; e += 64) {
        uint p = __builtin_nontemporal_load(csr + e);
        s += __uint_as_float((p & 0x7FFFu) << 16);
    }
#pragma unroll
    for (int off = 32; off; off >>= 1) s += __shfl_xor(s, off);
    float v = s * W1[lane] + b1[lane];
    __builtin_nontemporal_store(f2bf(fmaxf(v, 0.f)), out + (size_t)row * H + lane);
}

// fused layer: out[d,:] = relu( (sum_e w_e * x[src_e,:]) @ W + b )
// Block = 16 rows (4 waves x 4 passes). Gather: wave per row, CSR chunk held
// in registers, broadcast via v_readlane (SALU-assisted decode). agg rows ->
// bf16 LDS tile; epilogue: per-wave 16x16 MFMA tile of AG @ W + bias + relu.
__global__ __launch_bounds__(256) void layer_kernel(const int* __restrict__ rowptr,
        const uint* __restrict__ csr, const ushort* __restrict__ x,
        const float* __restrict__ W, const float* __restrict__ b,
        ushort* __restrict__ out, int N) {
    __shared__ alignas(16) ushort Wt[64][72];   // Wt[c][k] = bf16(W[k][c]), +8 pad
    __shared__ alignas(16) ushort AG[RPB][72];  // bf16 agg rows, +8 pad
    int tid = threadIdx.x;
    for (int i = tid; i < 64 * 64; i += 256) {  // stage W transposed as bf16
        int k = i >> 6, c = i & 63;
        Wt[c][k] = f2bf(W[i]);
    }
    __syncthreads();
    int lane = tid & 63, wid = tid >> 6;
    int rowbase = blockIdx.x * RPB;
    for (int p = 0; p < 4; ++p) {
        int trow = wid * 4 + p;
        int row = rowbase + trow;
        float agg = 0.f;
        if (row < N) {
            int beg = rowptr[row], end = rowptr[row + 1];
            int len = end - beg;
            for (int ck = 0; ck < len; ck += 64) {
                uint pv = 0u;                          // pad: w=0, src=0 (safe)
                int idx = beg + ck + lane;
                if (idx < end) pv = __builtin_nontemporal_load(csr + idx);
                int rem = len - ck;
                int grps = rem >= 64 ? 8 : ((rem + 7) >> 3);
#pragma unroll
                for (int g = 0; g < 8; ++g) {
                    if (g < grps) {
#pragma unroll
                        for (int j = 0; j < 8; ++j) {
                            uint s = (uint)__builtin_amdgcn_readlane((int)pv, g * 8 + j);
                            float wf = __uint_as_float((s & 0x7FFFu) << 16);
                            float xv = bf2f(x[((s >> 15) << 6) + (uint)lane]);
                            agg = fmaf(wf, xv, agg);
                        }
                    }
                }
            }
        }
        AG[trow][lane] = f2bf(agg);                    // same-wave write
    }
    __syncthreads();
    // MFMA epilogue: wave wid -> output cols [wid*16, wid*16+16)
    int c0 = wid * 16;
    int cl = lane & 15, kg = lane >> 4;                // kg in 0..3
    short8 a0 = *reinterpret_cast<const short8*>(&AG[cl][kg * 8]);
    short8 a1 = *reinterpret_cast<const short8*>(&AG[cl][32 + kg * 8]);
    short8 bb0 = *reinterpret_cast<const short8*>(&Wt[c0 + cl][kg * 8]);
    short8 bb1 = *reinterpret_cast<const short8*>(&Wt[c0 + cl][32 + kg * 8]);
    f32x4 acc = {0.f, 0.f, 0.f, 0.f};
    acc = __builtin_amdgcn_mfma_f32_16x16x32_bf16(a0, bb0, acc, 0, 0, 0);
    acc = __builtin_amdgcn_mfma_f32_16x16x32_bf16(a1, bb1, acc, 0, 0, 0);
    float bias = b[c0 + cl];
#pragma unroll
    for (int j = 0; j < 4; ++j) {                      // C: col=lane&15, row=kg*4+j
        int r = rowbase + kg * 4 + j;
        if (r < N) {
            float v = fmaxf(acc[j] + bias, 0.f);
            __builtin_nontemporal_store(f2bf(v), out + (size_t)r * H + c0 + cl);
        }
    }
}

// per-node dot with lin_w, LDS-binned segmented sum into 64 graphs
__global__ void pool_kernel(const ushort* __restrict__ x, const int* __restrict__ batch,
                            const float* __restrict__ linw, float* __restrict__ gsum,
                            float* __restrict__ gcnt, int N) {
    __shared__ float bins[NUM_GRAPHS];
    __shared__ float cnts[NUM_GRAPHS];
    int tid = threadIdx.x;
    if (tid < NUM_GRAPHS) { bins[tid] = 0.f; cnts[tid] = 0.f; }
    __syncthreads();
    int node = blockIdx.x * 256 + tid;
    if (node < N) {
        const uint4* xv = reinterpret_cast<const uint4*>(x + (size_t)node * H);
        float acc = 0.f;
#pragma unroll
        for (int k = 0; k < 8; ++k) {          // 8 x uint4 = 64 bf16
            uint4 u = xv[k];
            int c = k * 8;
            acc += bf2f((ushort)(u.x & 0xFFFF)) * linw[c + 0]
                 + bf2f((ushort)(u.x >> 16))    * linw[c + 1]
                 + bf2f((ushort)(u.y & 0xFFFF)) * linw[c + 2]
                 + bf2f((ushort)(u.y >> 16))    * linw[c + 3]
                 + bf2f((ushort)(u.z & 0xFFFF)) * linw[c + 4]
                 + bf2f((ushort)(u.z >> 16))    * linw[c + 5]
                 + bf2f((ushort)(u.w & 0xFFFF)) * linw[c + 6]
                 + bf2f((ushort)(u.w >> 16))    * linw[c + 7];
        }
        int g = batch[node];
        atomicAdd(&bins[g], acc);
        atomicAdd(&cnts[g], 1.f);
    }
    __syncthreads();
    if (tid < NUM_GRAPHS) {
        if (bins[tid] != 0.f || cnts[tid] != 0.f) {
            unsafeAtomicAdd(&gsum[tid], bins[tid]);
            unsafeAtomicAdd(&gcnt[tid], cnts[tid]);
        }
    }
}

__global__ void final_kernel(const float* __restrict__ gsum, const float* __restrict__ gcnt,
                             const float* __restrict__ lin_b, float* __restrict__ out) {
    int g = threadIdx.x;
    if (g < NUM_GRAPHS) out[g] = gsum[g] / fmaxf(gcnt[g], 1.f) + lin_b[0];
}

extern "C" void kernel_launch(void* const* d_in, const int* in_sizes, int n_in,
                              void* d_out, int out_size, void* d_ws, size_t ws_size,
                              hipStream_t stream) {
    const int*   edge_index = (const int*)d_in[0];
    const float* ew    = (const float*)d_in[1];
    const int*   batch = (const int*)d_in[2];
    const float* W1    = (const float*)d_in[4];
    const float* b1    = (const float*)d_in[5];
    const float* Wl[4] = {(const float*)d_in[6], (const float*)d_in[8],
                          (const float*)d_in[10], (const float*)d_in[12]};
    const float* bl[4] = {(const float*)d_in[7], (const float*)d_in[9],
                          (const float*)d_in[11], (const float*)d_in[13]};
    const float* linw  = (const float*)d_in[14];
    const float* linb  = (const float*)d_in[15];

    const int E = in_sizes[1];
    const int N = in_sizes[2];
    const int* src = edge_index;
    const int* dst = edge_index + E;
    const int NB = (N + BSIZE - 1) >> BSHIFT;

    // workspace layout
    char* base = (char*)d_ws;
    uint* csr = (uint*)base;
    size_t csrBytes = (((size_t)E * 4) + 255) & ~(size_t)255;
    ushort* bufA = (ushort*)(base + csrBytes);
    size_t featBytes = (size_t)N * H * 2;
    ushort* bufB = bufA + (size_t)N * H;
    int2* bucketed = (int2*)bufA;                       // aliases bufA+bufB (build only)
    size_t span = 2 * featBytes;
    size_t bktBytes = (size_t)E * 8;
    if (bktBytes > span) span = bktBytes;
    span = (span + 255) & ~(size_t)255;
    char* tail = base + csrBytes + span;
    int* rowptr    = (int*)tail;                        // N+1
    int* bucketCnt = rowptr + (N + 1);                  // MAXNB
    int* bucketPtr = bucketCnt + MAXNB;                 // MAXNB+1
    int* bucketCur = bucketPtr + MAXNB + 1;             // MAXNB
    float* gsum    = (float*)(bucketCur + MAXNB);       // 64
    float* gcnt    = gsum + NUM_GRAPHS;                 // 64

    const int chunks = (E + CHUNK - 1) / CHUNK;

    // ---- CSR build: bucketed counting sort (no global scan, L2-local scatter)
    hipMemsetAsync(bucketCnt, 0, MAXNB * sizeof(int), stream);
    bhist_kernel<<<chunks, 1024, 0, stream>>>(dst, bucketCnt, E, NB);
    bscan_kernel<<<1, MAXNB, 0, stream>>>(bucketCnt, bucketPtr, bucketCur, NB);
    part_kernel<<<chunks, 1024, 0, stream>>>(src, dst, ew, bucketCur, bucketed, E, NB);
    bsort_kernel<<<NB, 512, 0, stream>>>(bucketPtr, bucketed, csr, rowptr, N, E);

    // ---- layer 1 (collapsed: all-ones input through 1->64 linear)
    layer1_kernel<<<(N + 3) / 4, 256, 0, stream>>>(rowptr, csr, W1, b1, bufA, N);

    // ---- layers 2..5 (fused gather + MFMA matvec + bias + relu), bf16 features
    ushort* in = bufA;
    ushort* outb = bufB;
    for (int l = 0; l < 4; ++l) {
        layer_kernel<<<(N + RPB - 1) / RPB, 256, 0, stream>>>(rowptr, csr, in, Wl[l], bl[l], outb, N);
        ushort* t = in; in = outb; outb = t;
    }

    // ---- mean-pool per graph + final linear
    hipMemsetAsync(gsum, 0, 2 * NUM_GRAPHS * sizeof(float), stream);
    pool_kernel<<<(N + 255) / 256, 256, 0, stream>>>(in, batch, linw, gsum, gcnt, N);
    final_kernel<<<1, 64, 0, stream>>>(gsum, gcnt, linb, (float*)d_out);
}